// Round 2
// baseline (545.660 us; speedup 1.0000x reference)
//
#include <hip/hip_runtime.h>

// GNN fused pipeline on MI355X (gfx950), all fp32.
//   z   = BN(l2normalize(x))                      [elementwise, 1 wave/row]
//   CSR by dst (memset -> atomic histogram -> fused scan(+dinv) -> scatter)
//   y   = A_hat * z  (gather over CSR; half-wave float4 rows, 8 loads in flight)
//   out = leaky( [y|z] @ [W;rs_W] + (b+rs_b) )    [one K=256 fp32 GEMM]

#define NN 100000
#define DD 128
#define EE 1600000
#define BN_EPS 1e-5f
#define SLOPE 0.01f

__global__ void k_bias(const float* __restrict__ b, const float* __restrict__ rb,
                       float* __restrict__ bias2) {
  int i = threadIdx.x;
  if (i < DD) bias2[i] = b[i] + rb[i];
}

// fused row L2-normalize + BatchNorm(eval); one 64-lane wave per row, float2/lane
__global__ void k_norm_bn(const float* __restrict__ x,
                          const float* __restrict__ gamma,
                          const float* __restrict__ beta,
                          const float* __restrict__ mean,
                          const float* __restrict__ var,
                          float* __restrict__ z) {
  int row = blockIdx.x * 4 + (threadIdx.x >> 6);
  int lane = threadIdx.x & 63;
  if (row >= NN) return;
  float2 v = ((const float2*)(x + (size_t)row * DD))[lane];
  float ss = v.x * v.x + v.y * v.y;
  #pragma unroll
  for (int off = 32; off > 0; off >>= 1) ss += __shfl_xor(ss, off);
  float s = 1.0f / fmaxf(sqrtf(ss), 1e-12f);
  int c = lane * 2;
  float g0 = gamma[c]     * rsqrtf(var[c]     + BN_EPS);
  float g1 = gamma[c + 1] * rsqrtf(var[c + 1] + BN_EPS);
  float2 o;
  o.x = (v.x * s - mean[c])     * g0 + beta[c];
  o.y = (v.y * s - mean[c + 1]) * g1 + beta[c + 1];
  ((float2*)(z + (size_t)row * DD))[lane] = o;
}

__global__ void k_count(const int* __restrict__ dst, int* __restrict__ cnt) {
  int e = blockIdx.x * blockDim.x + threadIdx.x;
  if (e < EE) atomicAdd(&cnt[dst[e]], 1);
}

// ---- scan over cnt[N] -> rp[N] (exclusive), fused dinv = rsqrt(cnt+1) ----
__global__ void k_scan1(const int* __restrict__ in, int* __restrict__ outp,
                        int* __restrict__ bsum, float* __restrict__ dinv) {
  __shared__ int sh[256];
  int t = threadIdx.x;
  int i = blockIdx.x * 256 + t;
  int v = (i < NN) ? in[i] : 0;
  if (i < NN) dinv[i] = rsqrtf((float)(v + 1));  // +1 self-loop
  sh[t] = v;
  __syncthreads();
  for (int off = 1; off < 256; off <<= 1) {
    int a = (t >= off) ? sh[t - off] : 0;
    __syncthreads();
    sh[t] += a;
    __syncthreads();
  }
  if (i < NN) outp[i] = sh[t] - v;          // exclusive
  if (t == 255) bsum[blockIdx.x] = sh[255];
}

__global__ void k_scan2(int* __restrict__ bsum, int nb) {
  __shared__ int sh[512];
  int t = threadIdx.x;
  int v = (t < nb) ? bsum[t] : 0;
  sh[t] = v;
  __syncthreads();
  for (int off = 1; off < 512; off <<= 1) {
    int a = (t >= off) ? sh[t - off] : 0;
    __syncthreads();
    sh[t] += a;
    __syncthreads();
  }
  if (t < nb) bsum[t] = sh[t] - v;         // exclusive over block sums
}

// rp += block offset; cursor = rp (scatter uses absolute positions); rp[N] = E
__global__ void k_scan3(int* __restrict__ rp, const int* __restrict__ bsum,
                        int* __restrict__ cursor) {
  int i = blockIdx.x * 256 + threadIdx.x;
  if (i < NN) {
    int v = rp[i] + bsum[blockIdx.x];
    rp[i] = v;
    cursor[i] = v;
  }
  if (i == 0) rp[NN] = EE;
}

__global__ void k_scatter(const int* __restrict__ src, const int* __restrict__ dst,
                          int* __restrict__ cursor, int* __restrict__ csr) {
  int e = blockIdx.x * blockDim.x + threadIdx.x;
  if (e < EE) {
    int p = atomicAdd(&cursor[dst[e]], 1);
    csr[p] = src[e];
  }
}

// y[i] = dinv[i] * ( sum_{j in in-nbrs(i)} dinv[j]*z[j] + dinv[i]*z[i] )
// One wave per node. Lanes split into two 32-lane halves; each half reads full
// 512B rows via float4 (16B/lane) for alternating edges, 2 edges unrolled per
// half => 4 edge-rows (8 vmem loads incl. csr/dinv) in flight per iteration.
__global__ void k_aggregate(const float* __restrict__ z, const int* __restrict__ rp,
                            const int* __restrict__ csr, const float* __restrict__ dinv,
                            float* __restrict__ y) {
  int node = blockIdx.x * 4 + (threadIdx.x >> 6);
  int lane = threadIdx.x & 63;
  int half = lane >> 5;
  int l32  = lane & 31;
  if (node >= NN) return;
  int beg = rp[node], end = rp[node + 1];
  float di = dinv[node];
  const float4* zb = (const float4*)z;     // row stride = 32 float4
  float4 acc = make_float4(0.f, 0.f, 0.f, 0.f);
  int k = beg + half;                      // half 0: beg,beg+2,.. half 1: beg+1,beg+3,..
  for (; k + 2 < end; k += 4) {            // 2 edges per half per iter
    int j0 = csr[k];
    int j1 = csr[k + 2];
    float d0 = dinv[j0], d1 = dinv[j1];
    float4 a0 = zb[(size_t)j0 * 32 + l32];
    float4 a1 = zb[(size_t)j1 * 32 + l32];
    acc.x = fmaf(d1, a1.x, fmaf(d0, a0.x, acc.x));
    acc.y = fmaf(d1, a1.y, fmaf(d0, a0.y, acc.y));
    acc.z = fmaf(d1, a1.z, fmaf(d0, a0.z, acc.z));
    acc.w = fmaf(d1, a1.w, fmaf(d0, a0.w, acc.w));
  }
  for (; k < end; k += 2) {
    int j0 = csr[k];
    float d0 = dinv[j0];
    float4 a0 = zb[(size_t)j0 * 32 + l32];
    acc.x = fmaf(d0, a0.x, acc.x);
    acc.y = fmaf(d0, a0.y, acc.y);
    acc.z = fmaf(d0, a0.z, acc.z);
    acc.w = fmaf(d0, a0.w, acc.w);
  }
  // combine the two halves (both end up with the full sum)
  acc.x += __shfl_xor(acc.x, 32, 64);
  acc.y += __shfl_xor(acc.y, 32, 64);
  acc.z += __shfl_xor(acc.z, 32, 64);
  acc.w += __shfl_xor(acc.w, 32, 64);
  if (half == 0) {
    float4 zs = zb[(size_t)node * 32 + l32];
    float4 o;
    o.x = (acc.x + di * zs.x) * di;
    o.y = (acc.y + di * zs.y) * di;
    o.z = (acc.z + di * zs.z) * di;
    o.w = (acc.w + di * zs.w) * di;
    ((float4*)y)[(size_t)node * 32 + l32] = o;
  }
}

// out = leaky( [y|z](N x 256) @ [W;rs_W](256 x 128) + bias2 )
// 128x128 block tile, BK=32, 256 threads, 8x8 micro-tile. A transposed in LDS.
__global__ __launch_bounds__(256) void k_gemm(
    const float* __restrict__ y, const float* __restrict__ z,
    const float* __restrict__ W, const float* __restrict__ rsW,
    const float* __restrict__ bias2, float* __restrict__ out) {
  __shared__ float As[32][132];
  __shared__ float Bs[32][132];
  const int tid = threadIdx.x;
  const int ty = tid >> 4;        // 0..15 -> rows ty*8..ty*8+7
  const int tx = tid & 15;        // 0..15 -> cols {tx*4..+3} and {64+tx*4..+3}
  const int row0 = blockIdx.x * 128;

  float acc[8][8];
  #pragma unroll
  for (int i = 0; i < 8; ++i)
    #pragma unroll
    for (int j = 0; j < 8; ++j) acc[i][j] = 0.f;

  for (int kt = 0; kt < 8; ++kt) {
    const float* Ag = (kt < 4) ? y : z;
    const float* Bg = (kt < 4) ? W : rsW;
    const int kc = (kt & 3) * 32;
    #pragma unroll
    for (int i = 0; i < 4; ++i) {
      int lin = tid + i * 256;     // float4 index over [128][8]
      int r = lin >> 3, c4 = lin & 7;
      int gr = row0 + r;
      float4 v = make_float4(0.f, 0.f, 0.f, 0.f);
      if (gr < NN) v = *(const float4*)(Ag + (size_t)gr * DD + kc + c4 * 4);
      int c = c4 * 4;
      As[c + 0][r] = v.x; As[c + 1][r] = v.y; As[c + 2][r] = v.z; As[c + 3][r] = v.w;
    }
    #pragma unroll
    for (int i = 0; i < 4; ++i) {
      int lin = tid + i * 256;     // float4 index over [32][32]
      int r = lin >> 5, c4 = lin & 31;
      float4 v = *(const float4*)(Bg + (size_t)(kc + r) * DD + c4 * 4);
      *(float4*)&Bs[r][c4 * 4] = v;
    }
    __syncthreads();
    #pragma unroll
    for (int k = 0; k < 32; ++k) {
      float4 a0 = *(const float4*)&As[k][ty * 8];
      float4 a1 = *(const float4*)&As[k][ty * 8 + 4];
      float4 b0 = *(const float4*)&Bs[k][tx * 4];
      float4 b1 = *(const float4*)&Bs[k][64 + tx * 4];
      float a[8]  = {a0.x, a0.y, a0.z, a0.w, a1.x, a1.y, a1.z, a1.w};
      float bb[8] = {b0.x, b0.y, b0.z, b0.w, b1.x, b1.y, b1.z, b1.w};
      #pragma unroll
      for (int i = 0; i < 8; ++i)
        #pragma unroll
        for (int j = 0; j < 8; ++j)
          acc[i][j] = fmaf(a[i], bb[j], acc[i][j]);
    }
    __syncthreads();
  }

  float4 bb0 = *(const float4*)(bias2 + tx * 4);
  float4 bb1 = *(const float4*)(bias2 + 64 + tx * 4);
  float bB[8] = {bb0.x, bb0.y, bb0.z, bb0.w, bb1.x, bb1.y, bb1.z, bb1.w};
  #pragma unroll
  for (int i = 0; i < 8; ++i) {
    int gr = row0 + ty * 8 + i;
    if (gr >= NN) continue;
    float o[8];
    #pragma unroll
    for (int j = 0; j < 8; ++j) {
      float v = acc[i][j] + bB[j];
      o[j] = (v >= 0.f) ? v : SLOPE * v;
    }
    *(float4*)(out + (size_t)gr * DD + tx * 4)      = make_float4(o[0], o[1], o[2], o[3]);
    *(float4*)(out + (size_t)gr * DD + 64 + tx * 4) = make_float4(o[4], o[5], o[6], o[7]);
  }
}

extern "C" void kernel_launch(void* const* d_in, const int* in_sizes, int n_in,
                              void* d_out, int out_size, void* d_ws, size_t ws_size,
                              hipStream_t stream) {
  const float* x     = (const float*)d_in[0];
  const int*   ei    = (const int*)d_in[1];
  const float* W     = (const float*)d_in[2];
  const float* b     = (const float*)d_in[3];
  const float* gamma = (const float*)d_in[4];
  const float* beta  = (const float*)d_in[5];
  const float* mean  = (const float*)d_in[6];
  const float* var   = (const float*)d_in[7];
  const float* rsW   = (const float*)d_in[8];
  const float* rsb   = (const float*)d_in[9];
  float* out = (float*)d_out;
  const int* src = ei;         // edge_index[0]
  const int* dst = ei + EE;    // edge_index[1]

  float* z      = (float*)d_ws;
  float* y      = z + (size_t)NN * DD;
  int*   cnt    = (int*)(y + (size_t)NN * DD);
  float* dinv   = (float*)(cnt + NN);
  int*   rp     = (int*)(dinv + NN);
  int*   cursor = rp + NN + 1;
  int*   csr    = cursor + NN;
  int*   bsum   = csr + EE;
  float* bias2  = (float*)(bsum + 1024);

  const int EB = (EE + 255) / 256;   // 6250
  const int NB = (NN + 255) / 256;   // 391

  k_bias<<<1, 128, 0, stream>>>(b, rsb, bias2);
  k_norm_bn<<<NN / 4, 256, 0, stream>>>(x, gamma, beta, mean, var, z);
  hipMemsetAsync(cnt, 0, NN * sizeof(int), stream);
  k_count<<<EB, 256, 0, stream>>>(dst, cnt);
  k_scan1<<<NB, 256, 0, stream>>>(cnt, rp, bsum, dinv);
  k_scan2<<<1, 512, 0, stream>>>(bsum, NB);
  k_scan3<<<NB, 256, 0, stream>>>(rp, bsum, cursor);
  k_scatter<<<EB, 256, 0, stream>>>(src, dst, cursor, csr);
  k_aggregate<<<NN / 4, 256, 0, stream>>>(z, rp, csr, dinv, y);
  k_gemm<<<(NN + 127) / 128, 256, 0, stream>>>(y, z, W, rsW, bias2, out);
}

// Round 3
// 411.421 us; speedup vs baseline: 1.3263x; 1.3263x over previous
//
#include <hip/hip_runtime.h>

// GNN fused pipeline on MI355X (gfx950), all fp32.
//   z   = BN(l2normalize(x))                       [elementwise, 1 wave/row]
//   CSR by dst via two-level counting sort:
//     binA: coarse-bucket (dst>>10) binning, chunk-reserved coalesced writes
//     binB: per-bucket LDS histogram+scan -> dinv, startdeg, csr (XCD-local writes)
//   y   = A_hat * z  (gather over CSR; y lives in d_out)
//   out = leaky( [y|z] @ [W;rs_W] + (b+rs_b) )     [one K=256 fp32 GEMM]

#define NN 100000
#define DD 128
#define EE 1600000
#define BN_EPS 1e-5f
#define SLOPE 0.01f

#define NBKT 98          // ceil(NN / 1024)
#define BWID 1024        // nodes per bucket (dst >> 10)
#define CAPP 20480       // slack capacity per bucket (mean 16384, sd ~127)
#define EPB  8192        // edges per binA block

__global__ void k_init(const float* __restrict__ b, const float* __restrict__ rb,
                       float* __restrict__ bias2, int* __restrict__ gcur) {
  int i = threadIdx.x;
  if (i < DD) bias2[i] = b[i] + rb[i];
  if (i < NBKT) gcur[i] = i * CAPP;
}

// fused row L2-normalize + BatchNorm(eval); one 64-lane wave per row, float2/lane
__global__ void k_norm_bn(const float* __restrict__ x,
                          const float* __restrict__ gamma,
                          const float* __restrict__ beta,
                          const float* __restrict__ mean,
                          const float* __restrict__ var,
                          float* __restrict__ z) {
  int row = blockIdx.x * 4 + (threadIdx.x >> 6);
  int lane = threadIdx.x & 63;
  if (row >= NN) return;
  float2 v = ((const float2*)(x + (size_t)row * DD))[lane];
  float ss = v.x * v.x + v.y * v.y;
  #pragma unroll
  for (int off = 32; off > 0; off >>= 1) ss += __shfl_xor(ss, off);
  float s = 1.0f / fmaxf(sqrtf(ss), 1e-12f);
  int c = lane * 2;
  float g0 = gamma[c]     * rsqrtf(var[c]     + BN_EPS);
  float g1 = gamma[c + 1] * rsqrtf(var[c + 1] + BN_EPS);
  float2 o;
  o.x = (v.x * s - mean[c])     * g0 + beta[c];
  o.y = (v.y * s - mean[c + 1]) * g1 + beta[c + 1];
  ((float2*)(z + (size_t)row * DD))[lane] = o;
}

// Phase A: coarse binning. Per block: LDS histogram over 98 buckets, ONE global
// atomic per (block,bucket) reserves a contiguous chunk, then packed writes.
// pairs[] entry: (local_dst << 17) | src   (src < 2^17, local_dst < 2^10)
__global__ __launch_bounds__(256) void k_binA(const int* __restrict__ src,
                                              const int* __restrict__ dst,
                                              int* __restrict__ gcur,
                                              int* __restrict__ pairs) {
  __shared__ int hist[NBKT];
  __shared__ int base[NBKT];
  __shared__ int cur[NBKT];
  int t = threadIdx.x;
  if (t < NBKT) hist[t] = 0;
  __syncthreads();
  int e0 = blockIdx.x * EPB;
  #pragma unroll 4
  for (int i = 0; i < EPB / 256; ++i) {
    int e = e0 + i * 256 + t;
    if (e < EE) atomicAdd(&hist[dst[e] >> 10], 1);
  }
  __syncthreads();
  if (t < NBKT) {
    base[t] = atomicAdd(&gcur[t], hist[t]);   // absolute (gcur init = b*CAPP)
    cur[t] = 0;
  }
  __syncthreads();
  #pragma unroll 4
  for (int i = 0; i < EPB / 256; ++i) {
    int e = e0 + i * 256 + t;
    if (e < EE) {
      int d = dst[e], s = src[e];
      int bk = d >> 10;
      int r = atomicAdd(&cur[bk], 1);
      pairs[base[bk] + r] = ((d & 1023) << 17) | s;
    }
  }
}

// Phase B: one block per bucket. LDS histogram over the bucket's 1024 nodes,
// in-block scan -> dinv, startdeg{start,deg}; scatter csr into the bucket's
// exclusive region (stays in one XCD's L2, written back once).
__global__ __launch_bounds__(1024) void k_binB(const int* __restrict__ gcur,
                                               const int* __restrict__ pairs,
                                               int* __restrict__ csr,
                                               int2* __restrict__ startdeg,
                                               float* __restrict__ dinv) {
  __shared__ int hist[BWID];
  __shared__ int excl[BWID];
  __shared__ int wsum[16];
  int b = blockIdx.x, t = threadIdx.x;
  hist[t] = 0;
  __syncthreads();
  int pbase = b * CAPP;
  int cnt = gcur[b] - pbase;
  for (int i = t; i < cnt; i += BWID)
    atomicAdd(&hist[pairs[pbase + i] >> 17], 1);
  __syncthreads();
  // exclusive scan of hist[1024]
  int v = hist[t];
  int lane = t & 63, w = t >> 6;
  int incl = v;
  #pragma unroll
  for (int off = 1; off < 64; off <<= 1) {
    int n = __shfl_up(incl, off, 64);
    if (lane >= off) incl += n;
  }
  if (lane == 63) wsum[w] = incl;
  __syncthreads();
  if (t < 16) {
    int orig = wsum[t];
    int s = orig;
    #pragma unroll
    for (int off = 1; off < 16; off <<= 1) {
      int n = __shfl_up(s, off, 64);
      if (t >= off) s += n;
    }
    wsum[t] = s - orig;   // exclusive over wave sums
  }
  __syncthreads();
  int myexcl = (incl - v) + wsum[w];
  excl[t] = myexcl;
  int node = b * BWID + t;
  if (node < NN) {
    dinv[node] = rsqrtf((float)(v + 1));               // +1 self-loop
    startdeg[node] = make_int2(b * CAPP + myexcl, v);  // csr shares CAPP layout
  }
  __syncthreads();   // all regs captured before excl[] becomes a cursor
  for (int i = t; i < cnt; i += BWID) {
    int p = pairs[pbase + i];
    int pos = atomicAdd(&excl[p >> 17], 1);
    csr[b * CAPP + pos] = p & 0x1FFFF;
  }
}

// y[i] = dinv[i] * ( sum_{j in in-nbrs(i)} dinv[j]*z[j] + dinv[i]*z[i] )
// One wave per node; two 32-lane halves, float4/lane, 2 edges per half in flight.
__global__ void k_aggregate(const float* __restrict__ z,
                            const int2* __restrict__ startdeg,
                            const int* __restrict__ csr,
                            const float* __restrict__ dinv,
                            float* __restrict__ y) {
  int node = blockIdx.x * 4 + (threadIdx.x >> 6);
  int lane = threadIdx.x & 63;
  int half = lane >> 5;
  int l32  = lane & 31;
  if (node >= NN) return;
  int2 sd = startdeg[node];
  int beg = sd.x, end = sd.x + sd.y;
  float di = dinv[node];
  const float4* zb = (const float4*)z;     // row stride = 32 float4
  float4 acc = make_float4(0.f, 0.f, 0.f, 0.f);
  int k = beg + half;
  for (; k + 2 < end; k += 4) {
    int j0 = csr[k];
    int j1 = csr[k + 2];
    float d0 = dinv[j0], d1 = dinv[j1];
    float4 a0 = zb[(size_t)j0 * 32 + l32];
    float4 a1 = zb[(size_t)j1 * 32 + l32];
    acc.x = fmaf(d1, a1.x, fmaf(d0, a0.x, acc.x));
    acc.y = fmaf(d1, a1.y, fmaf(d0, a0.y, acc.y));
    acc.z = fmaf(d1, a1.z, fmaf(d0, a0.z, acc.z));
    acc.w = fmaf(d1, a1.w, fmaf(d0, a0.w, acc.w));
  }
  for (; k < end; k += 2) {
    int j0 = csr[k];
    float d0 = dinv[j0];
    float4 a0 = zb[(size_t)j0 * 32 + l32];
    acc.x = fmaf(d0, a0.x, acc.x);
    acc.y = fmaf(d0, a0.y, acc.y);
    acc.z = fmaf(d0, a0.z, acc.z);
    acc.w = fmaf(d0, a0.w, acc.w);
  }
  acc.x += __shfl_xor(acc.x, 32, 64);
  acc.y += __shfl_xor(acc.y, 32, 64);
  acc.z += __shfl_xor(acc.z, 32, 64);
  acc.w += __shfl_xor(acc.w, 32, 64);
  if (half == 0) {
    float4 zs = zb[(size_t)node * 32 + l32];
    float4 o;
    o.x = (acc.x + di * zs.x) * di;
    o.y = (acc.y + di * zs.y) * di;
    o.z = (acc.z + di * zs.z) * di;
    o.w = (acc.w + di * zs.w) * di;
    ((float4*)y)[(size_t)node * 32 + l32] = o;
  }
}

// out = leaky( [y|z](N x 256) @ [W;rs_W](256 x 128) + bias2 )
// 128x128 block tile, BK=32, 256 threads, 8x8 micro-tile. A transposed in LDS.
// y aliases out: each block reads only its own rows, then overwrites them.
__global__ __launch_bounds__(256) void k_gemm(
    const float* __restrict__ y, const float* __restrict__ z,
    const float* __restrict__ W, const float* __restrict__ rsW,
    const float* __restrict__ bias2, float* __restrict__ out) {
  __shared__ float As[32][132];
  __shared__ float Bs[32][132];
  const int tid = threadIdx.x;
  const int ty = tid >> 4;
  const int tx = tid & 15;
  const int row0 = blockIdx.x * 128;

  float acc[8][8];
  #pragma unroll
  for (int i = 0; i < 8; ++i)
    #pragma unroll
    for (int j = 0; j < 8; ++j) acc[i][j] = 0.f;

  for (int kt = 0; kt < 8; ++kt) {
    const float* Ag = (kt < 4) ? y : z;
    const float* Bg = (kt < 4) ? W : rsW;
    const int kc = (kt & 3) * 32;
    #pragma unroll
    for (int i = 0; i < 4; ++i) {
      int lin = tid + i * 256;     // float4 index over [128][8]
      int r = lin >> 3, c4 = lin & 7;
      int gr = row0 + r;
      float4 v = make_float4(0.f, 0.f, 0.f, 0.f);
      if (gr < NN) v = *(const float4*)(Ag + (size_t)gr * DD + kc + c4 * 4);
      int c = c4 * 4;
      As[c + 0][r] = v.x; As[c + 1][r] = v.y; As[c + 2][r] = v.z; As[c + 3][r] = v.w;
    }
    #pragma unroll
    for (int i = 0; i < 4; ++i) {
      int lin = tid + i * 256;     // float4 index over [32][32]
      int r = lin >> 5, c4 = lin & 31;
      float4 v = *(const float4*)(Bg + (size_t)(kc + r) * DD + c4 * 4);
      *(float4*)&Bs[r][c4 * 4] = v;
    }
    __syncthreads();
    #pragma unroll
    for (int k = 0; k < 32; ++k) {
      float4 a0 = *(const float4*)&As[k][ty * 8];
      float4 a1 = *(const float4*)&As[k][ty * 8 + 4];
      float4 b0 = *(const float4*)&Bs[k][tx * 4];
      float4 b1 = *(const float4*)&Bs[k][64 + tx * 4];
      float a[8]  = {a0.x, a0.y, a0.z, a0.w, a1.x, a1.y, a1.z, a1.w};
      float bb[8] = {b0.x, b0.y, b0.z, b0.w, b1.x, b1.y, b1.z, b1.w};
      #pragma unroll
      for (int i = 0; i < 8; ++i)
        #pragma unroll
        for (int j = 0; j < 8; ++j)
          acc[i][j] = fmaf(a[i], bb[j], acc[i][j]);
    }
    __syncthreads();
  }

  float4 bb0 = *(const float4*)(bias2 + tx * 4);
  float4 bb1 = *(const float4*)(bias2 + 64 + tx * 4);
  float bB[8] = {bb0.x, bb0.y, bb0.z, bb0.w, bb1.x, bb1.y, bb1.z, bb1.w};
  #pragma unroll
  for (int i = 0; i < 8; ++i) {
    int gr = row0 + ty * 8 + i;
    if (gr >= NN) continue;
    float o[8];
    #pragma unroll
    for (int j = 0; j < 8; ++j) {
      float v = acc[i][j] + bB[j];
      o[j] = (v >= 0.f) ? v : SLOPE * v;
    }
    *(float4*)(out + (size_t)gr * DD + tx * 4)      = make_float4(o[0], o[1], o[2], o[3]);
    *(float4*)(out + (size_t)gr * DD + 64 + tx * 4) = make_float4(o[4], o[5], o[6], o[7]);
  }
}

extern "C" void kernel_launch(void* const* d_in, const int* in_sizes, int n_in,
                              void* d_out, int out_size, void* d_ws, size_t ws_size,
                              hipStream_t stream) {
  const float* x     = (const float*)d_in[0];
  const int*   ei    = (const int*)d_in[1];
  const float* W     = (const float*)d_in[2];
  const float* b     = (const float*)d_in[3];
  const float* gamma = (const float*)d_in[4];
  const float* beta  = (const float*)d_in[5];
  const float* mean  = (const float*)d_in[6];
  const float* var   = (const float*)d_in[7];
  const float* rsW   = (const float*)d_in[8];
  const float* rsb   = (const float*)d_in[9];
  float* out = (float*)d_out;
  const int* src = ei;         // edge_index[0]
  const int* dst = ei + EE;    // edge_index[1]

  // workspace carve-up (~67 MB); y lives in d_out
  float* z        = (float*)d_ws;                       // NN*DD floats
  int2*  startdeg = (int2*)(z + (size_t)NN * DD);       // NN int2 (8B aligned)
  float* dinv     = (float*)(startdeg + NN);            // NN floats
  int*   gcur     = (int*)(dinv + NN);                  // NBKT (pad to 128)
  int*   pairs    = gcur + 128;                         // NBKT*CAPP ints
  int*   csr      = pairs + NBKT * CAPP;                // NBKT*CAPP ints
  float* bias2    = (float*)(csr + NBKT * CAPP);        // DD floats
  float* y        = out;

  k_init<<<1, 128, 0, stream>>>(b, rsb, bias2, gcur);
  k_norm_bn<<<NN / 4, 256, 0, stream>>>(x, gamma, beta, mean, var, z);
  k_binA<<<(EE + EPB - 1) / EPB, 256, 0, stream>>>(src, dst, gcur, pairs);
  k_binB<<<NBKT, 1024, 0, stream>>>(gcur, pairs, csr, startdeg, dinv);
  k_aggregate<<<NN / 4, 256, 0, stream>>>(z, startdeg, csr, dinv, y);
  k_gemm<<<(NN + 127) / 128, 256, 0, stream>>>(y, z, W, rsW, bias2, out);
}

// Round 4
// 354.839 us; speedup vs baseline: 1.5378x; 1.1595x over previous
//
#include <hip/hip_runtime.h>
#include <hip/hip_fp16.h>

// GNN fused pipeline on MI355X (gfx950).
//   z,zh = BN(l2normalize(x))  fp32 + fp16 copies   [elementwise]
//   CSR by dst via two-level counting sort (binA coarse, binB per-bucket)
//   y   = A_hat * z  (neighbor gather from fp16 zh, self-term fp32; y in d_out)
//   out = leaky( [y|z] @ [W;rs_W] + (b+rs_b) )      [one K=256 fp32 GEMM]

#define NN 100000
#define DD 128
#define EE 1600000
#define BN_EPS 1e-5f
#define SLOPE 0.01f

#define NBKT 98          // ceil(NN / 1024)
#define BWID 1024        // nodes per bucket (dst >> 10)
#define CAPP 20480       // slack capacity per bucket (mean 16384, sd ~127)
#define EPB  4096        // edges per binA block -> 391 blocks

struct __align__(8) H4 { __half2 a, b; };   // 4 halves = 8 bytes

__global__ void k_init(const float* __restrict__ b, const float* __restrict__ rb,
                       float* __restrict__ bias2, int* __restrict__ gcur) {
  int i = threadIdx.x;
  if (i < DD) bias2[i] = b[i] + rb[i];
  if (i < NBKT) gcur[i] = i * CAPP;
}

// fused row L2-normalize + BatchNorm(eval); one 64-lane wave per row, float2/lane
// emits fp32 z and fp16 zh
__global__ void k_norm_bn(const float* __restrict__ x,
                          const float* __restrict__ gamma,
                          const float* __restrict__ beta,
                          const float* __restrict__ mean,
                          const float* __restrict__ var,
                          float* __restrict__ z, __half* __restrict__ zh) {
  int row = blockIdx.x * 4 + (threadIdx.x >> 6);
  int lane = threadIdx.x & 63;
  if (row >= NN) return;
  float2 v = ((const float2*)(x + (size_t)row * DD))[lane];
  float ss = v.x * v.x + v.y * v.y;
  #pragma unroll
  for (int off = 32; off > 0; off >>= 1) ss += __shfl_xor(ss, off);
  float s = 1.0f / fmaxf(sqrtf(ss), 1e-12f);
  int c = lane * 2;
  float g0 = gamma[c]     * rsqrtf(var[c]     + BN_EPS);
  float g1 = gamma[c + 1] * rsqrtf(var[c + 1] + BN_EPS);
  float2 o;
  o.x = (v.x * s - mean[c])     * g0 + beta[c];
  o.y = (v.y * s - mean[c + 1]) * g1 + beta[c + 1];
  ((float2*)(z + (size_t)row * DD))[lane] = o;
  ((__half2*)(zh + (size_t)row * DD))[lane] = __floats2half2_rn(o.x, o.y);
}

// Phase A: coarse binning. Wave-parity-split LDS histograms halve same-address
// atomic serialization. ONE global atomic per (block,bucket) reserves a chunk.
// pairs[] entry: (local_dst << 17) | src
__global__ __launch_bounds__(256) void k_binA(const int* __restrict__ src,
                                              const int* __restrict__ dst,
                                              int* __restrict__ gcur,
                                              int* __restrict__ pairs) {
  __shared__ int hist[2][NBKT];
  __shared__ int cur[2][NBKT];
  int t = threadIdx.x;
  int w2 = (t >> 6) & 1;          // wave parity
  if (t < NBKT) { hist[0][t] = 0; hist[1][t] = 0; }
  __syncthreads();
  int e0 = blockIdx.x * EPB;
  #pragma unroll 4
  for (int i = 0; i < EPB / 256; ++i) {
    int e = e0 + i * 256 + t;
    if (e < EE) atomicAdd(&hist[w2][dst[e] >> 10], 1);
  }
  __syncthreads();
  if (t < NBKT) {
    int h0 = hist[0][t], h1 = hist[1][t];
    int b0 = atomicAdd(&gcur[t], h0 + h1);  // absolute (gcur init = b*CAPP)
    cur[0][t] = b0;
    cur[1][t] = b0 + h0;
  }
  __syncthreads();
  #pragma unroll 4
  for (int i = 0; i < EPB / 256; ++i) {
    int e = e0 + i * 256 + t;
    if (e < EE) {
      int d = dst[e], s = src[e];
      int bk = d >> 10;
      int r = atomicAdd(&cur[w2][bk], 1);
      pairs[r] = ((d & 1023) << 17) | s;
    }
  }
}

// Phase B: one block per bucket. LDS histogram over 1024 nodes, in-block scan
// -> dinv, startdeg; scatter csr within the bucket's exclusive region.
__global__ __launch_bounds__(1024) void k_binB(const int* __restrict__ gcur,
                                               const int* __restrict__ pairs,
                                               int* __restrict__ csr,
                                               int2* __restrict__ startdeg,
                                               float* __restrict__ dinv) {
  __shared__ int hist[BWID];
  __shared__ int excl[BWID];
  __shared__ int wsum[16];
  int b = blockIdx.x, t = threadIdx.x;
  hist[t] = 0;
  __syncthreads();
  int pbase = b * CAPP;
  int cnt = gcur[b] - pbase;
  for (int i = t; i < cnt; i += BWID)
    atomicAdd(&hist[pairs[pbase + i] >> 17], 1);
  __syncthreads();
  int v = hist[t];
  int lane = t & 63, w = t >> 6;
  int incl = v;
  #pragma unroll
  for (int off = 1; off < 64; off <<= 1) {
    int n = __shfl_up(incl, off, 64);
    if (lane >= off) incl += n;
  }
  if (lane == 63) wsum[w] = incl;
  __syncthreads();
  if (t < 16) {
    int orig = wsum[t];
    int s = orig;
    #pragma unroll
    for (int off = 1; off < 16; off <<= 1) {
      int n = __shfl_up(s, off, 64);
      if (t >= off) s += n;
    }
    wsum[t] = s - orig;
  }
  __syncthreads();
  int myexcl = (incl - v) + wsum[w];
  excl[t] = myexcl;
  int node = b * BWID + t;
  if (node < NN) {
    dinv[node] = rsqrtf((float)(v + 1));               // +1 self-loop
    startdeg[node] = make_int2(pbase + myexcl, v);
  }
  __syncthreads();
  for (int i = t; i < cnt; i += BWID) {
    int p = pairs[pbase + i];
    int pos = atomicAdd(&excl[p >> 17], 1);
    csr[pbase + pos] = p & 0x1FFFF;
  }
}

// y[i] = dinv[i] * ( sum_j dinv[j]*zh[j] + dinv[i]*z[i] )
// One wave per node; two 32-lane halves. Neighbor rows fp16 (256B, 8B/lane),
// 4 edges per half unrolled => 8 row-loads in flight per wave. Self-term fp32.
__global__ void k_aggregate(const float* __restrict__ z,
                            const __half* __restrict__ zh,
                            const int2* __restrict__ startdeg,
                            const int* __restrict__ csr,
                            const float* __restrict__ dinv,
                            float* __restrict__ y) {
  int node = blockIdx.x * 4 + (threadIdx.x >> 6);
  int lane = threadIdx.x & 63;
  int half = lane >> 5;
  int l32  = lane & 31;
  int2 sd = startdeg[node];
  int beg = sd.x, end = sd.x + sd.y;
  float di = dinv[node];
  const H4* zr = (const H4*)zh;            // row stride = 32 H4
  float4 acc = make_float4(0.f, 0.f, 0.f, 0.f);
  int k = beg + half;
  for (; k + 6 < end; k += 8) {            // 4 edges per half per iter
    int j0 = csr[k], j1 = csr[k + 2], j2 = csr[k + 4], j3 = csr[k + 6];
    float d0 = dinv[j0], d1 = dinv[j1], d2 = dinv[j2], d3 = dinv[j3];
    H4 a0 = zr[(size_t)j0 * 32 + l32];
    H4 a1 = zr[(size_t)j1 * 32 + l32];
    H4 a2 = zr[(size_t)j2 * 32 + l32];
    H4 a3 = zr[(size_t)j3 * 32 + l32];
    float2 f0a = __half22float2(a0.a), f0b = __half22float2(a0.b);
    float2 f1a = __half22float2(a1.a), f1b = __half22float2(a1.b);
    float2 f2a = __half22float2(a2.a), f2b = __half22float2(a2.b);
    float2 f3a = __half22float2(a3.a), f3b = __half22float2(a3.b);
    acc.x = fmaf(d0, f0a.x, fmaf(d1, f1a.x, fmaf(d2, f2a.x, fmaf(d3, f3a.x, acc.x))));
    acc.y = fmaf(d0, f0a.y, fmaf(d1, f1a.y, fmaf(d2, f2a.y, fmaf(d3, f3a.y, acc.y))));
    acc.z = fmaf(d0, f0b.x, fmaf(d1, f1b.x, fmaf(d2, f2b.x, fmaf(d3, f3b.x, acc.z))));
    acc.w = fmaf(d0, f0b.y, fmaf(d1, f1b.y, fmaf(d2, f2b.y, fmaf(d3, f3b.y, acc.w))));
  }
  for (; k < end; k += 2) {
    int j0 = csr[k];
    float d0 = dinv[j0];
    H4 a0 = zr[(size_t)j0 * 32 + l32];
    float2 f0a = __half22float2(a0.a), f0b = __half22float2(a0.b);
    acc.x = fmaf(d0, f0a.x, acc.x);
    acc.y = fmaf(d0, f0a.y, acc.y);
    acc.z = fmaf(d0, f0b.x, acc.z);
    acc.w = fmaf(d0, f0b.y, acc.w);
  }
  acc.x += __shfl_xor(acc.x, 32, 64);
  acc.y += __shfl_xor(acc.y, 32, 64);
  acc.z += __shfl_xor(acc.z, 32, 64);
  acc.w += __shfl_xor(acc.w, 32, 64);
  if (half == 0) {
    float4 zs = ((const float4*)z)[(size_t)node * 32 + l32];
    float4 o;
    o.x = (acc.x + di * zs.x) * di;
    o.y = (acc.y + di * zs.y) * di;
    o.z = (acc.z + di * zs.z) * di;
    o.w = (acc.w + di * zs.w) * di;
    ((float4*)y)[(size_t)node * 32 + l32] = o;
  }
}

// out = leaky( [y|z](N x 256) @ [W;rs_W](256 x 128) + bias2 )
// 128x128 block tile, BK=32, 256 threads, 8x8 micro-tile. A transposed in LDS.
// y aliases out: each block reads only its own rows, then overwrites them.
__global__ __launch_bounds__(256) void k_gemm(
    const float* __restrict__ y, const float* __restrict__ z,
    const float* __restrict__ W, const float* __restrict__ rsW,
    const float* __restrict__ bias2, float* __restrict__ out) {
  __shared__ float As[32][132];
  __shared__ float Bs[32][132];
  const int tid = threadIdx.x;
  const int ty = tid >> 4;
  const int tx = tid & 15;
  const int row0 = blockIdx.x * 128;

  float acc[8][8];
  #pragma unroll
  for (int i = 0; i < 8; ++i)
    #pragma unroll
    for (int j = 0; j < 8; ++j) acc[i][j] = 0.f;

  for (int kt = 0; kt < 8; ++kt) {
    const float* Ag = (kt < 4) ? y : z;
    const float* Bg = (kt < 4) ? W : rsW;
    const int kc = (kt & 3) * 32;
    #pragma unroll
    for (int i = 0; i < 4; ++i) {
      int lin = tid + i * 256;     // float4 index over [128][8]
      int r = lin >> 3, c4 = lin & 7;
      int gr = row0 + r;
      float4 v = make_float4(0.f, 0.f, 0.f, 0.f);
      if (gr < NN) v = *(const float4*)(Ag + (size_t)gr * DD + kc + c4 * 4);
      int c = c4 * 4;
      As[c + 0][r] = v.x; As[c + 1][r] = v.y; As[c + 2][r] = v.z; As[c + 3][r] = v.w;
    }
    #pragma unroll
    for (int i = 0; i < 4; ++i) {
      int lin = tid + i * 256;     // float4 index over [32][32]
      int r = lin >> 5, c4 = lin & 31;
      float4 v = *(const float4*)(Bg + (size_t)(kc + r) * DD + c4 * 4);
      *(float4*)&Bs[r][c4 * 4] = v;
    }
    __syncthreads();
    #pragma unroll
    for (int k = 0; k < 32; ++k) {
      float4 a0 = *(const float4*)&As[k][ty * 8];
      float4 a1 = *(const float4*)&As[k][ty * 8 + 4];
      float4 b0 = *(const float4*)&Bs[k][tx * 4];
      float4 b1 = *(const float4*)&Bs[k][64 + tx * 4];
      float a[8]  = {a0.x, a0.y, a0.z, a0.w, a1.x, a1.y, a1.z, a1.w};
      float bb[8] = {b0.x, b0.y, b0.z, b0.w, b1.x, b1.y, b1.z, b1.w};
      #pragma unroll
      for (int i = 0; i < 8; ++i)
        #pragma unroll
        for (int j = 0; j < 8; ++j)
          acc[i][j] = fmaf(a[i], bb[j], acc[i][j]);
    }
    __syncthreads();
  }

  float4 bb0 = *(const float4*)(bias2 + tx * 4);
  float4 bb1 = *(const float4*)(bias2 + 64 + tx * 4);
  float bB[8] = {bb0.x, bb0.y, bb0.z, bb0.w, bb1.x, bb1.y, bb1.z, bb1.w};
  #pragma unroll
  for (int i = 0; i < 8; ++i) {
    int gr = row0 + ty * 8 + i;
    if (gr >= NN) continue;
    float o[8];
    #pragma unroll
    for (int j = 0; j < 8; ++j) {
      float v = acc[i][j] + bB[j];
      o[j] = (v >= 0.f) ? v : SLOPE * v;
    }
    *(float4*)(out + (size_t)gr * DD + tx * 4)      = make_float4(o[0], o[1], o[2], o[3]);
    *(float4*)(out + (size_t)gr * DD + 64 + tx * 4) = make_float4(o[4], o[5], o[6], o[7]);
  }
}

extern "C" void kernel_launch(void* const* d_in, const int* in_sizes, int n_in,
                              void* d_out, int out_size, void* d_ws, size_t ws_size,
                              hipStream_t stream) {
  const float* x     = (const float*)d_in[0];
  const int*   ei    = (const int*)d_in[1];
  const float* W     = (const float*)d_in[2];
  const float* b     = (const float*)d_in[3];
  const float* gamma = (const float*)d_in[4];
  const float* beta  = (const float*)d_in[5];
  const float* mean  = (const float*)d_in[6];
  const float* var   = (const float*)d_in[7];
  const float* rsW   = (const float*)d_in[8];
  const float* rsb   = (const float*)d_in[9];
  float* out = (float*)d_out;
  const int* src = ei;         // edge_index[0]
  const int* dst = ei + EE;    // edge_index[1]

  // workspace carve-up (~94 MB); y lives in d_out
  float*  z        = (float*)d_ws;                      // NN*DD f32
  __half* zh       = (__half*)(z + (size_t)NN * DD);    // NN*DD f16
  int2*   startdeg = (int2*)(zh + (size_t)NN * DD);     // NN int2
  float*  dinv     = (float*)(startdeg + NN);           // NN f32
  int*    gcur     = (int*)(dinv + NN);                 // NBKT (pad 128)
  int*    pairs    = gcur + 128;                        // NBKT*CAPP
  int*    csr      = pairs + NBKT * CAPP;               // NBKT*CAPP
  float*  bias2    = (float*)(csr + NBKT * CAPP);       // DD f32
  float*  y        = out;

  k_init<<<1, 128, 0, stream>>>(b, rsb, bias2, gcur);
  k_norm_bn<<<NN / 4, 256, 0, stream>>>(x, gamma, beta, mean, var, z, zh);
  k_binA<<<(EE + EPB - 1) / EPB, 256, 0, stream>>>(src, dst, gcur, pairs);
  k_binB<<<NBKT, 1024, 0, stream>>>(gcur, pairs, csr, startdeg, dinv);
  k_aggregate<<<NN / 4, 256, 0, stream>>>(z, zh, startdeg, csr, dinv, y);
  k_gemm<<<(NN + 127) / 128, 256, 0, stream>>>(y, z, W, rsW, bias2, out);
}

// Round 5
// 298.173 us; speedup vs baseline: 1.8300x; 1.1900x over previous
//
#include <hip/hip_runtime.h>
#include <hip/hip_fp16.h>

// GNN fused pipeline on MI355X (gfx950).
//   Ah[N][256] fp16 = [y | z]:
//     norm_bn: z = BN(l2normalize(x)) -> Ah cols 128..255
//     CSR by dst via two-level counting sort (binA coarse, binB per-bucket)
//     aggregate: y = A_hat * z (fp16 gather) -> Ah cols 0..127
//   out = leaky( Ah @ WhT^T + bias2 )  via fp16 MFMA 16x16x32, fp32 accum

#define NN 100000
#define DD 128
#define EE 1600000
#define BN_EPS 1e-5f
#define SLOPE 0.01f

#define NBKT 98          // ceil(NN / 1024)
#define BWID 1024        // nodes per bucket (dst >> 10)
#define CAPP 20480       // slack capacity per bucket (mean 16327, sd ~128)
#define EPB  4096        // edges per binA block -> 391 blocks

struct __align__(8) H4 { __half2 a, b; };   // 4 halves = 8 bytes

typedef _Float16 f16x8 __attribute__((ext_vector_type(8)));
typedef float    f32x4 __attribute__((ext_vector_type(4)));

// blocks 0..127: WhT[n][k] = fp16 of [W;rs_W][k][n]; block 128: bias2 + gcur init
__global__ void k_prep(const float* __restrict__ W, const float* __restrict__ rsW,
                       const float* __restrict__ b, const float* __restrict__ rb,
                       __half* __restrict__ WhT, float* __restrict__ bias2,
                       int* __restrict__ gcur) {
  int blk = blockIdx.x, t = threadIdx.x;
  if (blk == 128) {
    if (t < DD) bias2[t] = b[t] + rb[t];
    if (t < NBKT) gcur[t] = t * CAPP;
    return;
  }
  float v = (t < 128) ? W[t * 128 + blk] : rsW[(t - 128) * 128 + blk];
  WhT[blk * 256 + t] = __float2half(v);
}

// fused row L2-normalize + BatchNorm(eval); one 64-lane wave per row;
// writes fp16 z into Ah cols 128..255
__global__ void k_norm_bn(const float* __restrict__ x,
                          const float* __restrict__ gamma,
                          const float* __restrict__ beta,
                          const float* __restrict__ mean,
                          const float* __restrict__ var,
                          __half* __restrict__ Ah) {
  int row = blockIdx.x * 4 + (threadIdx.x >> 6);
  int lane = threadIdx.x & 63;
  if (row >= NN) return;
  float2 v = ((const float2*)(x + (size_t)row * DD))[lane];
  float ss = v.x * v.x + v.y * v.y;
  #pragma unroll
  for (int off = 32; off > 0; off >>= 1) ss += __shfl_xor(ss, off);
  float s = 1.0f / fmaxf(sqrtf(ss), 1e-12f);
  int c = lane * 2;
  float g0 = gamma[c]     * rsqrtf(var[c]     + BN_EPS);
  float g1 = gamma[c + 1] * rsqrtf(var[c + 1] + BN_EPS);
  float ox = (v.x * s - mean[c])     * g0 + beta[c];
  float oy = (v.y * s - mean[c + 1]) * g1 + beta[c + 1];
  ((__half2*)(Ah + (size_t)row * 256 + 128))[lane] = __floats2half2_rn(ox, oy);
}

// Phase A: coarse binning; wave-parity-split LDS histograms; one global atomic
// per (block,bucket). pairs[] entry: (local_dst << 17) | src
__global__ __launch_bounds__(256) void k_binA(const int* __restrict__ src,
                                              const int* __restrict__ dst,
                                              int* __restrict__ gcur,
                                              int* __restrict__ pairs) {
  __shared__ int hist[2][NBKT];
  __shared__ int cur[2][NBKT];
  int t = threadIdx.x;
  int w2 = (t >> 6) & 1;
  if (t < NBKT) { hist[0][t] = 0; hist[1][t] = 0; }
  __syncthreads();
  int e0 = blockIdx.x * EPB;
  #pragma unroll 4
  for (int i = 0; i < EPB / 256; ++i) {
    int e = e0 + i * 256 + t;
    if (e < EE) atomicAdd(&hist[w2][dst[e] >> 10], 1);
  }
  __syncthreads();
  if (t < NBKT) {
    int h0 = hist[0][t], h1 = hist[1][t];
    int b0 = atomicAdd(&gcur[t], h0 + h1);
    cur[0][t] = b0;
    cur[1][t] = b0 + h0;
  }
  __syncthreads();
  #pragma unroll 4
  for (int i = 0; i < EPB / 256; ++i) {
    int e = e0 + i * 256 + t;
    if (e < EE) {
      int d = dst[e], s = src[e];
      int bk = d >> 10;
      int r = atomicAdd(&cur[w2][bk], 1);
      pairs[r] = ((d & 1023) << 17) | s;
    }
  }
}

// Phase B: one block per bucket; LDS histogram + scan -> dinv, startdeg; csr
// scatter within the bucket's exclusive region.
__global__ __launch_bounds__(1024) void k_binB(const int* __restrict__ gcur,
                                               const int* __restrict__ pairs,
                                               int* __restrict__ csr,
                                               int2* __restrict__ startdeg,
                                               float* __restrict__ dinv) {
  __shared__ int hist[BWID];
  __shared__ int excl[BWID];
  __shared__ int wsum[16];
  int b = blockIdx.x, t = threadIdx.x;
  hist[t] = 0;
  __syncthreads();
  int pbase = b * CAPP;
  int cnt = gcur[b] - pbase;
  for (int i = t; i < cnt; i += BWID)
    atomicAdd(&hist[pairs[pbase + i] >> 17], 1);
  __syncthreads();
  int v = hist[t];
  int lane = t & 63, w = t >> 6;
  int incl = v;
  #pragma unroll
  for (int off = 1; off < 64; off <<= 1) {
    int n = __shfl_up(incl, off, 64);
    if (lane >= off) incl += n;
  }
  if (lane == 63) wsum[w] = incl;
  __syncthreads();
  if (t < 16) {
    int orig = wsum[t];
    int s = orig;
    #pragma unroll
    for (int off = 1; off < 16; off <<= 1) {
      int n = __shfl_up(s, off, 64);
      if (t >= off) s += n;
    }
    wsum[t] = s - orig;
  }
  __syncthreads();
  int myexcl = (incl - v) + wsum[w];
  excl[t] = myexcl;
  int node = b * BWID + t;
  if (node < NN) {
    dinv[node] = rsqrtf((float)(v + 1));               // +1 self-loop
    startdeg[node] = make_int2(pbase + myexcl, v);
  }
  __syncthreads();
  for (int i = t; i < cnt; i += BWID) {
    int p = pairs[pbase + i];
    int pos = atomicAdd(&excl[p >> 17], 1);
    csr[pbase + pos] = p & 0x1FFFF;
  }
}

// y[i] = dinv[i] * ( sum_j dinv[j]*z[j] + dinv[i]*z[i] ), all fp16 reads from
// Ah cols 128..255 (H4 offset 32, row stride 64 H4); writes fp16 y to cols 0..127.
__global__ void k_aggregate(__half* __restrict__ Ah,
                            const int2* __restrict__ startdeg,
                            const int* __restrict__ csr,
                            const float* __restrict__ dinv) {
  int node = blockIdx.x * 4 + (threadIdx.x >> 6);
  int lane = threadIdx.x & 63;
  int half = lane >> 5;
  int l32  = lane & 31;
  int2 sd = startdeg[node];
  int beg = sd.x, end = sd.x + sd.y;
  float di = dinv[node];
  const H4* zr = (const H4*)Ah;            // row stride 64 H4; z at +32
  float4 acc = make_float4(0.f, 0.f, 0.f, 0.f);
  int k = beg + half;
  for (; k + 6 < end; k += 8) {            // 4 edges per half per iter
    int j0 = csr[k], j1 = csr[k + 2], j2 = csr[k + 4], j3 = csr[k + 6];
    float d0 = dinv[j0], d1 = dinv[j1], d2 = dinv[j2], d3 = dinv[j3];
    H4 a0 = zr[(size_t)j0 * 64 + 32 + l32];
    H4 a1 = zr[(size_t)j1 * 64 + 32 + l32];
    H4 a2 = zr[(size_t)j2 * 64 + 32 + l32];
    H4 a3 = zr[(size_t)j3 * 64 + 32 + l32];
    float2 f0a = __half22float2(a0.a), f0b = __half22float2(a0.b);
    float2 f1a = __half22float2(a1.a), f1b = __half22float2(a1.b);
    float2 f2a = __half22float2(a2.a), f2b = __half22float2(a2.b);
    float2 f3a = __half22float2(a3.a), f3b = __half22float2(a3.b);
    acc.x = fmaf(d0, f0a.x, fmaf(d1, f1a.x, fmaf(d2, f2a.x, fmaf(d3, f3a.x, acc.x))));
    acc.y = fmaf(d0, f0a.y, fmaf(d1, f1a.y, fmaf(d2, f2a.y, fmaf(d3, f3a.y, acc.y))));
    acc.z = fmaf(d0, f0b.x, fmaf(d1, f1b.x, fmaf(d2, f2b.x, fmaf(d3, f3b.x, acc.z))));
    acc.w = fmaf(d0, f0b.y, fmaf(d1, f1b.y, fmaf(d2, f2b.y, fmaf(d3, f3b.y, acc.w))));
  }
  for (; k < end; k += 2) {
    int j0 = csr[k];
    float d0 = dinv[j0];
    H4 a0 = zr[(size_t)j0 * 64 + 32 + l32];
    float2 f0a = __half22float2(a0.a), f0b = __half22float2(a0.b);
    acc.x = fmaf(d0, f0a.x, acc.x);
    acc.y = fmaf(d0, f0a.y, acc.y);
    acc.z = fmaf(d0, f0b.x, acc.z);
    acc.w = fmaf(d0, f0b.y, acc.w);
  }
  acc.x += __shfl_xor(acc.x, 32, 64);
  acc.y += __shfl_xor(acc.y, 32, 64);
  acc.z += __shfl_xor(acc.z, 32, 64);
  acc.w += __shfl_xor(acc.w, 32, 64);
  if (half == 0) {
    H4 zs = zr[(size_t)node * 64 + 32 + l32];
    float2 za = __half22float2(zs.a), zb2 = __half22float2(zs.b);
    H4 o;
    o.a = __floats2half2_rn((acc.x + di * za.x) * di, (acc.y + di * za.y) * di);
    o.b = __floats2half2_rn((acc.z + di * zb2.x) * di, (acc.w + di * zb2.y) * di);
    ((H4*)Ah)[(size_t)node * 64 + l32] = o;
  }
}

// out = leaky( Ah(N x 256) @ WhT^T + bias2 ) via mfma_f32_16x16x32_f16.
// LDS-free: 4 waves/block, each wave 32 rows x 128 cols (16 tiles of 16x16).
// Fragment layout: A row = lane&15, k = (lane>>4)*8+i (contiguous 16B load);
// B col = lane&15, same k (contiguous rows of WhT). C: col=lane&15,
// row=(lane>>4)*4+reg.
__global__ __launch_bounds__(256) void k_gemm(
    const __half* __restrict__ Ah, const __half* __restrict__ WhT,
    const float* __restrict__ bias2, float* __restrict__ out) {
  const int tid = threadIdx.x;
  const int w  = tid >> 6;
  const int l  = tid & 63;
  const int lm = l & 15;
  const int lk = l >> 4;
  const int row0 = blockIdx.x * 128 + w * 32;

  int rA0 = row0 + lm;
  int rA1 = row0 + 16 + lm;
  if (rA0 >= NN) rA0 = NN - 1;   // clamp; stores are guarded
  if (rA1 >= NN) rA1 = NN - 1;

  f32x4 acc0[8], acc1[8];
  #pragma unroll
  for (int c = 0; c < 8; ++c) {
    acc0[c] = (f32x4)(0.f);
    acc1[c] = (f32x4)(0.f);
  }

  const __half* a0p = Ah + (size_t)rA0 * 256 + lk * 8;
  const __half* a1p = Ah + (size_t)rA1 * 256 + lk * 8;
  const __half* bp  = WhT + (size_t)lm * 256 + lk * 8;

  #pragma unroll
  for (int ks = 0; ks < 8; ++ks) {
    f16x8 a0 = *(const f16x8*)(a0p + ks * 32);
    f16x8 a1 = *(const f16x8*)(a1p + ks * 32);
    #pragma unroll
    for (int c = 0; c < 8; ++c) {
      f16x8 b = *(const f16x8*)(bp + (size_t)c * 16 * 256 + ks * 32);
      acc0[c] = __builtin_amdgcn_mfma_f32_16x16x32_f16(a0, b, acc0[c], 0, 0, 0);
      acc1[c] = __builtin_amdgcn_mfma_f32_16x16x32_f16(a1, b, acc1[c], 0, 0, 0);
    }
  }

  int orow0 = row0 + lk * 4;
  int orow1 = row0 + 16 + lk * 4;
  #pragma unroll
  for (int c = 0; c < 8; ++c) {
    int col = c * 16 + lm;
    float bs = bias2[col];
    #pragma unroll
    for (int r = 0; r < 4; ++r) {
      int g0 = orow0 + r;
      if (g0 < NN) {
        float v = acc0[c][r] + bs;
        out[(size_t)g0 * 128 + col] = (v >= 0.f) ? v : SLOPE * v;
      }
      int g1 = orow1 + r;
      if (g1 < NN) {
        float v = acc1[c][r] + bs;
        out[(size_t)g1 * 128 + col] = (v >= 0.f) ? v : SLOPE * v;
      }
    }
  }
}

extern "C" void kernel_launch(void* const* d_in, const int* in_sizes, int n_in,
                              void* d_out, int out_size, void* d_ws, size_t ws_size,
                              hipStream_t stream) {
  const float* x     = (const float*)d_in[0];
  const int*   ei    = (const int*)d_in[1];
  const float* W     = (const float*)d_in[2];
  const float* b     = (const float*)d_in[3];
  const float* gamma = (const float*)d_in[4];
  const float* beta  = (const float*)d_in[5];
  const float* mean  = (const float*)d_in[6];
  const float* var   = (const float*)d_in[7];
  const float* rsW   = (const float*)d_in[8];
  const float* rsb   = (const float*)d_in[9];
  float* out = (float*)d_out;
  const int* src = ei;         // edge_index[0]
  const int* dst = ei + EE;    // edge_index[1]

  // workspace carve-up (~68 MB)
  __half* Ah       = (__half*)d_ws;                     // NN*256 f16
  int2*   startdeg = (int2*)(Ah + (size_t)NN * 256);    // NN int2
  float*  dinv     = (float*)(startdeg + NN);           // NN f32
  int*    gcur     = (int*)(dinv + NN);                 // NBKT (pad 128)
  int*    pairs    = gcur + 128;                        // NBKT*CAPP
  int*    csr      = pairs + NBKT * CAPP;               // NBKT*CAPP
  __half* WhT      = (__half*)(csr + NBKT * CAPP);      // 128*256 f16
  float*  bias2    = (float*)(WhT + 128 * 256);         // DD f32

  k_prep<<<129, 256, 0, stream>>>(W, rsW, b, rsb, WhT, bias2, gcur);
  k_norm_bn<<<NN / 4, 256, 0, stream>>>(x, gamma, beta, mean, var, Ah);
  k_binA<<<(EE + EPB - 1) / EPB, 256, 0, stream>>>(src, dst, gcur, pairs);
  k_binB<<<NBKT, 1024, 0, stream>>>(gcur, pairs, csr, startdeg, dinv);
  k_aggregate<<<NN / 4, 256, 0, stream>>>(Ah, startdeg, csr, dinv);
  k_gemm<<<(NN + 127) / 128, 256, 0, stream>>>(Ah, WhT, bias2, out);
}